// Round 7
// baseline (33.342 us; speedup 1.0000x reference)
//
#include <hip/hip_runtime.h>

// Problem constants (match reference)
#define BQ 32
#define TT 20000
#define NN 200
#define S3 600              // 3*N
#define BLKS_PER_B 79       // ceil(20000 / 256) blocks per batch
#define NXCD 8

typedef float f32x4 __attribute__((ext_vector_type(4)));

// ---------------------------------------------------------------------------
// Shared compute: four distinct products T2[u][v] = Mij * S^u * Mjk * S^v * Mki
// (S = diag(1,1,-1)); all 8 Frobenius errors derived from them.
// ---------------------------------------------------------------------------
__device__ __forceinline__ void compute_errs(
    const float Mij[9], const float Mjk[9], const float Mki[9], float res[8])
{
    float N1[2][9];
#pragma unroll
    for (int p = 0; p < 3; ++p) {
#pragma unroll
        for (int r = 0; r < 3; ++r) {
            float c = Mij[p*3+0] * Mjk[0*3+r] + Mij[p*3+1] * Mjk[1*3+r];
            float d = Mij[p*3+2] * Mjk[2*3+r];
            N1[0][p*3+r] = c + d;
            N1[1][p*3+r] = c - d;
        }
    }
    float err[2][2];
#pragma unroll
    for (int u = 0; u < 2; ++u) {
        float T2p[9], T2m[9];
#pragma unroll
        for (int p = 0; p < 3; ++p) {
#pragma unroll
            for (int s = 0; s < 3; ++s) {
                float c = N1[u][p*3+0] * Mki[0*3+s] + N1[u][p*3+1] * Mki[1*3+s];
                float d = N1[u][p*3+2] * Mki[2*3+s];
                T2p[p*3+s] = c + d;
                T2m[p*3+s] = c - d;
            }
        }
#pragma unroll
        for (int v = 0; v < 2; ++v) {
            const float* T2 = (v == 0) ? T2p : T2m;
            float ss = 0.0f;
#pragma unroll
            for (int e = 0; e < 9; ++e) ss += T2[e] * T2[e];
            float diag = T2[0] + T2[4] + (((u ^ v) & 1) ? -T2[8] : T2[8]);
            float e2 = ss - 2.0f * diag + 3.0f;
            err[u][v] = sqrtf(fmaxf(e2, 0.0f));
        }
    }
#pragma unroll
    for (int m = 0; m < 8; ++m) {
        int a = (m >> 2) & 1, bb = (m >> 1) & 1, c = m & 1;
        res[m] = err[a ^ bb][bb ^ c];
    }
}

// ---------------------------------------------------------------------------
// Fused direct kernel with XCD-batch locality.
// Block mapping: xcd = g & 7, seq = g >> 3, batch = (seq/79)*8 + xcd.
// Each XCD walks its 4 batches sequentially, so the live H[b] working set
// per XCD is ~1-2 batches (1.44-2.9 MB) and fits the 4 MB per-XCD L2 —
// the 12B-row gather overfetch is then L2-served, not HBM-served.
// Mapping is a perf heuristic only; correctness is order-independent.
// ---------------------------------------------------------------------------
__global__ __launch_bounds__(256) void fused_err_kernel(
    const float* __restrict__ H,
    const int*   __restrict__ trip,
    float*       __restrict__ out)
{
    const int g   = blockIdx.x;            // 2528 blocks = 8 xcd * 4 groups * 79
    const int xcd = g & (NXCD - 1);
    const int seq = g >> 3;                // 0..315
    const int bg  = seq / BLKS_PER_B;      // 0..3
    const int b   = bg * NXCD + xcd;       // batch 0..31
    const int tb  = seq - bg * BLKS_PER_B;
    const int t   = tb * 256 + threadIdx.x;
    if (t >= TT) return;

    const int i = trip[3 * t + 0];
    const int j = trip[3 * t + 1];
    const int k = trip[3 * t + 2];

    const float* __restrict__ Hb = H + (size_t)b * (S3 * S3);

    float Mij[9], Mjk[9], Mki[9];
    const int ri = 3 * i, rj = 3 * j, rk = 3 * k;
#pragma unroll
    for (int p = 0; p < 3; ++p) {
        // 12B row-segments; memcpy lets the compiler emit global_load_dwordx3
        __builtin_memcpy(&Mij[3*p], Hb + (size_t)(ri + p) * S3 + rj, 12);
        __builtin_memcpy(&Mjk[3*p], Hb + (size_t)(rj + p) * S3 + rk, 12);
        __builtin_memcpy(&Mki[3*p], Hb + (size_t)(rk + p) * S3 + ri, 12);
    }

    float res[8];
    compute_errs(Mij, Mjk, Mki, res);

    // NT stores: keep the 20.5 MB output stream out of L2 so H stays resident
    f32x4* o4 = reinterpret_cast<f32x4*>(out + ((size_t)b * TT + t) * 8);
    f32x4 lo, hi;
    lo.x = res[0]; lo.y = res[1]; lo.z = res[2]; lo.w = res[3];
    hi.x = res[4]; hi.y = res[5]; hi.z = res[6]; hi.w = res[7];
    __builtin_nontemporal_store(lo, o4);
    __builtin_nontemporal_store(hi, o4 + 1);
}

extern "C" void kernel_launch(void* const* d_in, const int* in_sizes, int n_in,
                              void* d_out, int out_size, void* d_ws, size_t ws_size,
                              hipStream_t stream)
{
    const float* H    = (const float*)d_in[0];
    const int*   trip = (const int*)d_in[1];
    float*       out  = (float*)d_out;

    const int grid = NXCD * 4 * BLKS_PER_B;   // 2528 blocks, 256 threads each
    fused_err_kernel<<<grid, 256, 0, stream>>>(H, trip, out);
}